// Round 15
// baseline (173.411 us; speedup 1.0000x reference)
//
#include <hip/hip_runtime.h>
#include <hip/hip_bf16.h>
#include <math.h>

typedef __attribute__((ext_vector_type(8))) short short8;
typedef __attribute__((ext_vector_type(4))) float f32x4;

#define NCH 128
#define CT 16

__device__ __forceinline__ unsigned short f2bf(float f) {
  unsigned u = __builtin_bit_cast(unsigned, f);
  u += 0x7fffu + ((u >> 16) & 1u);
  return (unsigned short)(u >> 16);
}
__device__ __forceinline__ float bf2f(unsigned short u) {
  return __builtin_bit_cast(float, (unsigned)u << 16);
}
__device__ __forceinline__ float sigm(float x) { return 1.f / (1.f + __expf(-x)); }
// exp(x) for tiny x (|x| <= 0.07 here): 3-term Taylor, rel err < 1e-6
__device__ __forceinline__ float exps(float x) {
  return 1.f + x * (1.f + x * (0.5f + x * 0.16666667f));
}

__device__ __forceinline__ void stage16(const void* g, void* l) {
  __builtin_amdgcn_global_load_lds(
      (const __attribute__((address_space(1))) unsigned int*)(unsigned long long)g,
      (__attribute__((address_space(3))) unsigned int*)(unsigned)(unsigned long long)l,
      16, 0, 0);
}

// ---------------- prep uber-kernel ----------------
__global__ __launch_bounds__(256) void prep_uber(
    const float* __restrict__ x, const float* __restrict__ conv_w,
    const float* __restrict__ A_log, const float* __restrict__ in_proj_w,
    const float* __restrict__ gate_w, const float* __restrict__ o_proj_w,
    unsigned short* __restrict__ xb, unsigned short* __restrict__ cwt,
    float* __restrict__ cAb, unsigned short* __restrict__ wzt,
    unsigned short* __restrict__ gwt, unsigned short* __restrict__ owt) {
  __shared__ float tile[32][33];
  int bx = blockIdx.x;
  if (bx < 2050) {
    int idx = (bx * 256 + threadIdx.x) * 4;
    if (idx >= 2050 * 1024) return;
    int row = idx >> 10, col = idx & 1023;
    float v0 = 0.f, v1 = 0.f, v2 = 0.f, v3 = 0.f;
    if (row >= 2) {
      const float4 v = *(const float4*)(x + (size_t)(row - 2) * 1024 + col);
      v0 = v.x; v1 = v.y; v2 = v.z; v3 = v.w;
    }
    unsigned long long pk = (unsigned long long)f2bf(v0)
        | ((unsigned long long)f2bf(v1) << 16)
        | ((unsigned long long)f2bf(v2) << 32)
        | ((unsigned long long)f2bf(v3) << 48);
    *(unsigned long long*)(xb + idx) = pk;
    return;
  }
  bx -= 2050;
  if (bx < 8192) {
    int idx = bx * 256 + threadIdx.x;
    int d = idx >> 10, i = idx & 1023;
    const float* p = conv_w + (size_t)d * 3072 + (size_t)i * 3;
    unsigned short* q = cwt + (size_t)d * 3072 + i;
    q[0] = f2bf(p[0]);
    q[1024] = f2bf(p[1]);
    q[2048] = f2bf(p[2]);
    return;
  }
  bx -= 8192;
  if (bx < 128) {
    int i = bx * 256 + threadIdx.x;
    cAb[i] = log1pf(__expf(A_log[i]));  // softplus (natural log)
    return;
  }
  bx -= 128;
  const float* W;
  unsigned short* Wt;
  int src_ld, col_off, rowsI, n0, i0;
  if (bx < 2048) {
    W = in_proj_w; Wt = wzt; src_ld = 4096; col_off = 2048; rowsI = 1024;
    n0 = (bx & 63) * 32; i0 = (bx >> 6) * 32;
  } else if (bx < 2048 + 4096) {
    int b = bx - 2048;
    W = gate_w; Wt = gwt; src_ld = 2048; col_off = 0; rowsI = 2048;
    n0 = (b & 63) * 32; i0 = (b >> 6) * 32;
  } else {
    int b = bx - 2048 - 4096;
    W = o_proj_w; Wt = owt; src_ld = 1024; col_off = 0; rowsI = 2048;
    n0 = (b & 31) * 32; i0 = (b >> 5) * 32;
  }
  int tx = threadIdx.x & 31, ty = threadIdx.x >> 5;
#pragma unroll
  for (int rr = 0; rr < 32; rr += 8)
    tile[ty + rr][tx] = W[(size_t)(i0 + ty + rr) * src_ld + col_off + n0 + tx];
  __syncthreads();
#pragma unroll
  for (int rr = 0; rr < 32; rr += 8)
    Wt[(size_t)(n0 + ty + rr) * rowsI + i0 + tx] = f2bf(tile[tx][ty + rr]);
}

// ---------------- 128x64 rect GEMM body: 2buf, 1-ahead counted vmcnt(6), 3 blocks/CU ----------------
// MODE 0: outb = bf16(v)   MODE 1: outf = v   MODE 3: outb = bf16(sigm(v))
template <int MODE>
__device__ __forceinline__ void gemm_rect_body(
    const unsigned short* __restrict__ A, int lda,
    const unsigned short* __restrict__ Bt, int ldb, int K,
    const float* __restrict__ bias,
    float* __restrict__ outf, int ldo,
    unsigned short* __restrict__ outb,
    int bm, int bn, char* smem) {
  constexpr int BM = 128, BN = 64;
  constexpr int IA = 4, IB = 2, L = IA + IB;
  unsigned short (*As)[BM * 64] = (unsigned short(*)[BM * 64])smem;            // 2x16KB
  unsigned short (*Bs)[BN * 64] = (unsigned short(*)[BN * 64])(smem + 32768);  // 2x8KB

  const int tid = threadIdx.x;
  const int lane = tid & 63;
  const int w = tid >> 6;
  const int wr = w >> 1, wc = w & 1;

  f32x4 acc[4][2];
#pragma unroll
  for (int m = 0; m < 4; ++m)
#pragma unroll
    for (int n = 0; n < 2; ++n)
#pragma unroll
      for (int j = 0; j < 4; ++j) acc[m][n][j] = 0.f;

  const int srow = lane >> 3;
  const int sslot = (lane & 7) ^ srow;
  const unsigned short* Ab = A + (size_t)(bm * BM + srow) * lda + sslot * 8;
  const unsigned short* Bb = Bt + (size_t)(bn * BN + srow) * ldb + sslot * 8;

  const int r = lane & 15;
  const int g = lane >> 4;
  const int nk = K >> 6;

  auto stage = [&](int buf, int k0) {
#pragma unroll
    for (int i = 0; i < IA; ++i) {
      const int cb = w * IA + i;
      stage16(Ab + (size_t)(cb * 8) * lda + k0, &As[buf][cb * 512]);
    }
#pragma unroll
    for (int i = 0; i < IB; ++i) {
      const int cb = w * IB + i;
      stage16(Bb + (size_t)(cb * 8) * ldb + k0, &Bs[buf][cb * 512]);
    }
  };

  auto compute = [&](int buf) {
#pragma unroll
    for (int kk = 0; kk < 64; kk += 32) {
      const int sb = (kk >> 3) + g;
      short8 af[4], bfr[2];
#pragma unroll
      for (int m = 0; m < 4; ++m) {
        const int R = wr * 64 + m * 16 + r;
        af[m] = *(const short8*)&As[buf][R * 64 + ((sb ^ (R & 7)) << 3)];
      }
#pragma unroll
      for (int n = 0; n < 2; ++n) {
        const int R = wc * 32 + n * 16 + r;
        bfr[n] = *(const short8*)&Bs[buf][R * 64 + ((sb ^ (R & 7)) << 3)];
      }
#pragma unroll
      for (int m = 0; m < 4; ++m)
#pragma unroll
        for (int n = 0; n < 2; ++n)
          acc[m][n] = __builtin_amdgcn_mfma_f32_16x16x32_bf16(af[m], bfr[n], acc[m][n], 0, 0, 0);
    }
  };

  stage(0, 0);
  int cur = 0;
  for (int kt = 0; kt < nk; ++kt) {
    if (kt + 1 < nk) {
      stage(cur ^ 1, (kt + 1) * 64);
      asm volatile("s_waitcnt vmcnt(%c0)" ::"i"(L) : "memory");
    } else {
      asm volatile("s_waitcnt vmcnt(0)" ::: "memory");
    }
    __builtin_amdgcn_s_barrier();
    __builtin_amdgcn_sched_barrier(0);
    compute(cur);
    __builtin_amdgcn_s_barrier();
    cur ^= 1;
  }

  const int cc = lane & 15;
  const int cr = g * 4;
#pragma unroll
  for (int m = 0; m < 4; ++m) {
#pragma unroll
    for (int n = 0; n < 2; ++n) {
      const int col = bn * BN + wc * 32 + n * 16 + cc;
      const float bv = bias[col];
#pragma unroll
      for (int j = 0; j < 4; ++j) {
        const int row = bm * BM + wr * 64 + m * 16 + cr + j;
        const size_t o = (size_t)row * ldo + col;
        float v = acc[m][n][j] + bv;
        if (MODE == 0) { outb[o] = f2bf(v); }
        else if (MODE == 1) { outf[o] = v; }
        else { outb[o] = f2bf(sigm(v)); }
      }
    }
  }
}

// conv (ly<32) + z (ly>=32) merged, XCD-swizzled over 1024 blocks
__global__ __launch_bounds__(256, 3) void gemm_convz(
    const unsigned short* __restrict__ xb,
    const unsigned short* __restrict__ cwt,
    const unsigned short* __restrict__ wzt,
    const float* __restrict__ conv_b,
    const float* __restrict__ z_b,
    unsigned short* __restrict__ xcb,
    unsigned short* __restrict__ zpre_b) {
  __shared__ __attribute__((aligned(16))) char smem[49152];
  const int id = blockIdx.x + blockIdx.y * 16;      // [0,1024)
  const int logical = (id & 7) * 128 + (id >> 3);   // bijective XCD swizzle
  const int bm = logical & 15;
  const int ly = logical >> 4;                      // [0,64)
  const bool isz = ly >= 32;
  gemm_rect_body<0>(isz ? xb + 2048 : xb, 1024,
                    isz ? wzt : cwt, isz ? 1024 : 3072, isz ? 1024 : 3072,
                    isz ? z_b : conv_b, nullptr, 2048,
                    isz ? zpre_b : xcb,
                    bm, isz ? ly - 32 : ly, smem);
}

// ---------------- gate (128x64, MODE3, y<32) + bcdt (y>=32) ----------------
#define RB 4
__global__ __launch_bounds__(256, 3) void gemm_gate_bcdt(
    const unsigned short* __restrict__ xcb,
    const unsigned short* __restrict__ gwt,
    const float* __restrict__ gate_b,
    unsigned short* __restrict__ gpre_b,
    const float* __restrict__ xpw, const float* __restrict__ xpb,
    float* __restrict__ Bc, float* __restrict__ Cc, float* __restrict__ dt) {
  __shared__ __attribute__((aligned(16))) char smem[49152];
  const int tid = threadIdx.x;
  const int lane = tid & 63;
  const int w = tid >> 6;

  if (blockIdx.y >= 32) {
    // ---- bcdt path (LDS overlay: row 32KB + pj 4KB) ----
    float (*row)[2048] = (float(*)[2048])smem;
    float (*pj)[8][32] = (float(*)[8][32])(smem + 32768);
    const int b = (blockIdx.y - 32) * 16 + blockIdx.x;  // [0,512)
    const int s0 = b * RB;
    for (int i = tid; i < RB * 256; i += 256) {
      int ri = i >> 8, c8 = i & 255;
      short8 v = *(const short8*)&xcb[(size_t)(s0 + ri) * 2048 + c8 * 8];
#pragma unroll
      for (int j = 0; j < 8; ++j) row[ri][c8 * 8 + j] = bf2f((unsigned short)v[j]);
    }
    __syncthreads();
    {
      float l = 0.f;
      for (int i = lane; i < 2048; i += 64) l += row[w][i];
#pragma unroll
      for (int off = 32; off > 0; off >>= 1) l += __shfl_down(l, off);
      if (lane == 0) dt[s0 + w] = sigm(l * (1.f / 2048.f)) + 0.001f;
    }
    const int j = tid & 31, seg = tid >> 5;
    float acc[RB] = {0.f, 0.f, 0.f, 0.f};
    const int kbase = seg * 256;
    for (int k = 0; k < 256; ++k) {
      float wv2 = xpw[(size_t)(kbase + k) * 32 + j];
#pragma unroll
      for (int ri = 0; ri < RB; ++ri) acc[ri] += row[ri][kbase + k] * wv2;
    }
#pragma unroll
    for (int ri = 0; ri < RB; ++ri) pj[ri][seg][j] = acc[ri];
    __syncthreads();
    if (tid < 32 * RB) {
      int ri = tid >> 5, jj = tid & 31;
      float v = xpb[jj];
#pragma unroll
      for (int q = 0; q < 8; ++q) v += pj[ri][q][jj];
      if (jj < 16) Bc[(size_t)(s0 + ri) * 16 + jj] = v;
      else Cc[(size_t)(s0 + ri) * 16 + jj - 16] = v;
    }
    return;
  }

  // ---- gate GEMM path: 128x64, K=2048 ----
  gemm_rect_body<3>(xcb, 2048, gwt, 2048, 2048, gate_b, nullptr, 2048, gpre_b,
                    blockIdx.x, blockIdx.y, smem);
}

// ---------------- out-proj: 64x64 3-buffer, XCD-swizzled (R13-proven) ----------------
__global__ __launch_bounds__(256, 2) void gemm_out(
    const unsigned short* __restrict__ A, int lda,
    const unsigned short* __restrict__ Bt, int ldb, int K,
    const float* __restrict__ bias,
    float* __restrict__ outf, int ldo) {
  constexpr int L = 4;
  __shared__ unsigned short As[3][64 * 64];
  __shared__ unsigned short Bs[3][64 * 64];
  const int tid = threadIdx.x;
  const int lane = tid & 63;
  const int w = tid >> 6;
  const int wr = w >> 1, wc = w & 1;
  const int id = blockIdx.x + blockIdx.y * 32;  // [0,512)
  const int logical = (id & 7) * 64 + (id >> 3);
  const int bm = logical & 31, bn = logical >> 5;

  f32x4 acc[2][2];
#pragma unroll
  for (int m = 0; m < 2; ++m)
#pragma unroll
    for (int n = 0; n < 2; ++n)
#pragma unroll
      for (int j = 0; j < 4; ++j) acc[m][n][j] = 0.f;

  const int srow = lane >> 3;
  const int sslot = (lane & 7) ^ srow;
  const unsigned short* Ab = A + (size_t)(bm * 64 + srow) * lda + sslot * 8;
  const unsigned short* Bb = Bt + (size_t)(bn * 64 + srow) * ldb + sslot * 8;
  const int r = lane & 15;
  const int g = lane >> 4;
  const int nk = K >> 6;

  auto stage = [&](int buf, int k0) {
#pragma unroll
    for (int i = 0; i < 2; ++i) {
      const int cb = w * 2 + i;
      stage16(Ab + (size_t)(cb * 8) * lda + k0, &As[buf][cb * 512]);
      stage16(Bb + (size_t)(cb * 8) * ldb + k0, &Bs[buf][cb * 512]);
    }
  };
  auto compute = [&](int buf) {
#pragma unroll
    for (int kk = 0; kk < 64; kk += 32) {
      const int sb = (kk >> 3) + g;
      short8 af[2], bfr[2];
#pragma unroll
      for (int m = 0; m < 2; ++m) {
        const int R = wr * 32 + m * 16 + r;
        af[m] = *(const short8*)&As[buf][R * 64 + ((sb ^ (R & 7)) << 3)];
      }
#pragma unroll
      for (int n = 0; n < 2; ++n) {
        const int R = wc * 32 + n * 16 + r;
        bfr[n] = *(const short8*)&Bs[buf][R * 64 + ((sb ^ (R & 7)) << 3)];
      }
#pragma unroll
      for (int m = 0; m < 2; ++m)
#pragma unroll
        for (int n = 0; n < 2; ++n)
          acc[m][n] = __builtin_amdgcn_mfma_f32_16x16x32_bf16(af[m], bfr[n], acc[m][n], 0, 0, 0);
    }
  };

  stage(0, 0);
  stage(1, 64);
  int cur = 0, nxt = 2;
  for (int kt = 0; kt < nk; ++kt) {
    if (kt + 2 < nk) {
      stage(nxt, (kt + 2) * 64);
      asm volatile("s_waitcnt vmcnt(%c0)" ::"i"(2 * L) : "memory");
    } else if (kt + 1 < nk) {
      asm volatile("s_waitcnt vmcnt(%c0)" ::"i"(L) : "memory");
    } else {
      asm volatile("s_waitcnt vmcnt(0)" ::: "memory");
    }
    __builtin_amdgcn_s_barrier();
    __builtin_amdgcn_sched_barrier(0);
    compute(cur);
    __builtin_amdgcn_s_barrier();
    cur = (cur == 2) ? 0 : cur + 1;
    nxt = (nxt == 2) ? 0 : nxt + 1;
  }

  const int cc = lane & 15;
  const int cr = g * 4;
#pragma unroll
  for (int m = 0; m < 2; ++m)
#pragma unroll
    for (int n = 0; n < 2; ++n) {
      const int col = bn * 64 + wc * 32 + n * 16 + cc;
      const float bv = bias[col];
#pragma unroll
      for (int j = 0; j < 4; ++j) {
        const int row = bm * 64 + wr * 32 + m * 16 + cr + j;
        outf[(size_t)row * ldo + col] = acc[m][n][j] + bv;
      }
    }
}

// ---------------- scan: local pass (u = xcb * gpre; Taylor exp) ----------------
__global__ __launch_bounds__(256) void scan_local(const float* __restrict__ cAb,
                                                  const float* __restrict__ dt,
                                                  const float* __restrict__ Bc,
                                                  const float* __restrict__ Cc,
                                                  const unsigned short* __restrict__ xcb,
                                                  const unsigned short* __restrict__ gpre,
                                                  const float* __restrict__ Dp,
                                                  unsigned short* __restrict__ yloc,
                                                  unsigned short* __restrict__ Hend) {
  const int d0 = blockIdx.x * 256;
  const int d = d0 + threadIdx.x;
  const int c = blockIdx.y;
  __shared__ float sU[CT][256];
  __shared__ float sB[CT][16], sC[CT][16], sdt[CT];
  for (int i = threadIdx.x; i < CT * 32; i += 256) {
    int t = i >> 5, c8 = i & 31;
    size_t base = (size_t)(c * CT + t) * 2048 + d0 + c8 * 8;
    short8 vx = *(const short8*)&xcb[base];
    short8 vg = *(const short8*)&gpre[base];
#pragma unroll
    for (int j = 0; j < 8; ++j)
      sU[t][c8 * 8 + j] = bf2f((unsigned short)vx[j]) * bf2f((unsigned short)vg[j]);
  }
  for (int i = threadIdx.x; i < CT * 16; i += 256) {
    sB[i >> 4][i & 15] = Bc[(size_t)c * CT * 16 + i];
    sC[i >> 4][i & 15] = Cc[(size_t)c * CT * 16 + i];
  }
  if (threadIdx.x < CT) sdt[threadIdx.x] = dt[c * CT + threadIdx.x];
  __syncthreads();
  float cA[16], h[16];
#pragma unroll
  for (int n = 0; n < 16; ++n) {
    cA[n] = cAb[(size_t)d * 16 + n];
    h[n] = 0.f;
  }
  const float Dv = Dp[d];
  for (int t = 0; t < CT; ++t) {
    const float dtv = sdt[t];
    const float uv = sU[t][threadIdx.x];
    const float du = dtv * uv;
    float y = Dv * uv;
#pragma unroll
    for (int n = 0; n < 16; ++n) {
      float ab = exps(cA[n] * dtv);
      h[n] = ab * (h[n] + sB[t][n] * du);
      y += h[n] * sC[t][n];
    }
    yloc[(size_t)(c * CT + t) * 2048 + d] = f2bf(y);
  }
#pragma unroll
  for (int n = 0; n < 16; ++n) Hend[(size_t)c * 32768 + (size_t)d * 16 + n] = f2bf(h[n]);
}

// ---------------- scan: carry (in-place, bf16 H, Taylor exp) ----------------
__global__ __launch_bounds__(256) void scan_carry(const float* __restrict__ cAb,
                                                  const float* __restrict__ dt,
                                                  unsigned short* H) {
  const int g = blockIdx.x * 256 + threadIdx.x;
  __shared__ float sdt[2048];
  __shared__ float sS[NCH];
  for (int i = threadIdx.x; i < 2048; i += 256) sdt[i] = dt[i];
  __syncthreads();
  if (threadIdx.x < NCH) {
    float s = 0.f;
#pragma unroll
    for (int t = 0; t < CT; ++t) s += sdt[threadIdx.x * CT + t];
    sS[threadIdx.x] = s;
  }
  __syncthreads();
  const float cA = cAb[g];
  float h = 0.f;
  for (int cb = 0; cb < NCH; cb += 16) {
    float hl[16];
#pragma unroll
    for (int i = 0; i < 16; ++i) hl[i] = bf2f(H[(size_t)(cb + i) * 32768 + g]);
#pragma unroll
    for (int i = 0; i < 16; ++i) {
      H[(size_t)(cb + i) * 32768 + g] = f2bf(h);
      h = exps(cA * sS[cb + i]) * h + hl[i];
    }
  }
}

// ---------------- scan: final (parallel correction + gate, Taylor exp) ----------------
__global__ __launch_bounds__(256) void scan_final(const float* __restrict__ cAb,
                                                  const float* __restrict__ dt,
                                                  const float* __restrict__ Cc,
                                                  const unsigned short* __restrict__ yloc,
                                                  const unsigned short* __restrict__ zpre,
                                                  const unsigned short* __restrict__ H,
                                                  unsigned short* __restrict__ ob) {
  const int d = blockIdx.x * 256 + threadIdx.x;
  const int c = blockIdx.y;
  __shared__ float sC[CT][16], sT[CT], sdt[CT];
  for (int i = threadIdx.x; i < CT * 16; i += 256) sC[i >> 4][i & 15] = Cc[(size_t)c * CT * 16 + i];
  if (threadIdx.x < CT) sdt[threadIdx.x] = dt[c * CT + threadIdx.x];
  __syncthreads();
  if (threadIdx.x < CT) {
    float a = 0.f;
    for (int t = 0; t <= threadIdx.x; ++t) a += sdt[t];
    sT[threadIdx.x] = a;
  }
  __syncthreads();
  float cA[16], h0[16];
#pragma unroll
  for (int n = 0; n < 16; ++n) {
    cA[n] = cAb[(size_t)d * 16 + n];
    h0[n] = bf2f(H[(size_t)c * 32768 + (size_t)d * 16 + n]);
  }
  for (int t = 0; t < CT; ++t) {
    const size_t idx = (size_t)(c * CT + t) * 2048 + d;
    const float Tt = sT[t];
    float y = bf2f(yloc[idx]);
#pragma unroll
    for (int n = 0; n < 16; ++n) y += sC[t][n] * exps(cA[n] * Tt) * h0[n];
    ob[idx] = f2bf(y * sigm(bf2f(zpre[idx])));
  }
}

// ---------------- launch ----------------
extern "C" void kernel_launch(void* const* d_in, const int* in_sizes, int n_in,
                              void* d_out, int out_size, void* d_ws, size_t ws_size,
                              hipStream_t stream) {
  (void)in_sizes; (void)n_in; (void)out_size; (void)ws_size;
  const float* x = (const float*)d_in[0];
  const float* in_proj_w = (const float*)d_in[1];
  const float* in_proj_b = (const float*)d_in[2];
  const float* conv_w = (const float*)d_in[3];
  const float* conv_b = (const float*)d_in[4];
  const float* A_log = (const float*)d_in[5];
  const float* Dp = (const float*)d_in[6];
  const float* x_proj_w = (const float*)d_in[7];
  const float* x_proj_b = (const float*)d_in[8];
  const float* gate_w = (const float*)d_in[9];
  const float* gate_b = (const float*)d_in[10];
  const float* o_proj_w = (const float*)d_in[11];
  const float* o_proj_b = (const float*)d_in[12];

  char* ws = (char*)d_ws;
  size_t off = 0;
  unsigned short* xb = (unsigned short*)(ws + off); off += (size_t)2050 * 1024 * 2;
  off = (off + 255) & ~(size_t)255;
  unsigned short* cwt = (unsigned short*)(ws + off); off += (size_t)2048 * 3072 * 2;
  unsigned short* wzt = (unsigned short*)(ws + off); off += (size_t)2048 * 1024 * 2;
  unsigned short* gwt = (unsigned short*)(ws + off); off += (size_t)2048 * 2048 * 2;
  unsigned short* owt = (unsigned short*)(ws + off); off += (size_t)1024 * 2048 * 2;
  unsigned short* xcb = (unsigned short*)(ws + off); off += (size_t)2048 * 2048 * 2;
  unsigned short* zpre_b = (unsigned short*)(ws + off); off += (size_t)2048 * 2048 * 2;
  unsigned short* gpre_b = (unsigned short*)(ws + off); off += (size_t)2048 * 2048 * 2;
  unsigned short* yloc = (unsigned short*)(ws + off); off += (size_t)2048 * 2048 * 2;
  float* dtv = (float*)(ws + off); off += (size_t)2048 * 4;
  float* Bc = (float*)(ws + off); off += (size_t)2048 * 16 * 4;
  float* Cc = (float*)(ws + off); off += (size_t)2048 * 16 * 4;
  float* cAb = (float*)(ws + off); off += (size_t)32768 * 4;
  unsigned short* H = (unsigned short*)(ws + off); off += (size_t)NCH * 32768 * 2;
  unsigned short* ob = yloc;  // alias: scan_final reads yloc[idx] before writing ob[idx]

  prep_uber<<<18562, 256, 0, stream>>>(x, conv_w, A_log, in_proj_w, gate_w, o_proj_w,
                                       xb, cwt, cAb, wzt, gwt, owt);

  // conv [K=3072] + z [K=1024] merged, 128x64 2buf, 1024 blocks, 3/CU, XCD-swizzled
  gemm_convz<<<dim3(16, 64), 256, 0, stream>>>(xb, cwt, wzt, conv_b, in_proj_b + 2048, xcb, zpre_b);

  // gate 128x64 2buf (y<32, 512 blocks) + bcdt (y in [32,64), 512 blocks), 3/CU
  gemm_gate_bcdt<<<dim3(16, 64), 256, 0, stream>>>(xcb, gwt, gate_b, gpre_b,
                                                   x_proj_w, x_proj_b, Bc, Cc, dtv);

  scan_local<<<dim3(8, NCH), 256, 0, stream>>>(cAb, dtv, Bc, Cc, xcb, gpre_b, Dp, yloc, H);
  scan_carry<<<128, 256, 0, stream>>>(cAb, dtv, H);
  scan_final<<<dim3(8, NCH), 256, 0, stream>>>(cAb, dtv, Cc, yloc, zpre_b, H, ob);

  // output projection [2048x1024, K=2048], XCD-swizzled
  gemm_out<<<dim3(32, 16), 256, 0, stream>>>(ob, 2048, owt, 2048, 2048, o_proj_b, (float*)d_out, 1024);
}

// Round 16
// 151.597 us; speedup vs baseline: 1.1439x; 1.1439x over previous
//
#include <hip/hip_runtime.h>
#include <hip/hip_bf16.h>
#include <math.h>

typedef __attribute__((ext_vector_type(8))) short short8;
typedef __attribute__((ext_vector_type(4))) float f32x4;

#define NCH 128
#define CT 16

__device__ __forceinline__ unsigned short f2bf(float f) {
  unsigned u = __builtin_bit_cast(unsigned, f);
  u += 0x7fffu + ((u >> 16) & 1u);
  return (unsigned short)(u >> 16);
}
__device__ __forceinline__ float bf2f(unsigned short u) {
  return __builtin_bit_cast(float, (unsigned)u << 16);
}
__device__ __forceinline__ float sigm(float x) { return 1.f / (1.f + __expf(-x)); }
// exp(x) for tiny x (|x| <= 0.07 here): 3-term Taylor, rel err < 1e-6
__device__ __forceinline__ float exps(float x) {
  return 1.f + x * (1.f + x * (0.5f + x * 0.16666667f));
}

__device__ __forceinline__ void stage16(const void* g, void* l) {
  __builtin_amdgcn_global_load_lds(
      (const __attribute__((address_space(1))) unsigned int*)(unsigned long long)g,
      (__attribute__((address_space(3))) unsigned int*)(unsigned)(unsigned long long)l,
      16, 0, 0);
}

// ---------------- prep uber-kernel ----------------
__global__ __launch_bounds__(256) void prep_uber(
    const float* __restrict__ x, const float* __restrict__ conv_w,
    const float* __restrict__ A_log, const float* __restrict__ in_proj_w,
    const float* __restrict__ gate_w, const float* __restrict__ o_proj_w,
    unsigned short* __restrict__ xb, unsigned short* __restrict__ cwt,
    float* __restrict__ cAb, unsigned short* __restrict__ wzt,
    unsigned short* __restrict__ gwt, unsigned short* __restrict__ owt) {
  __shared__ float tile[32][33];
  int bx = blockIdx.x;
  if (bx < 2050) {
    int idx = (bx * 256 + threadIdx.x) * 4;
    if (idx >= 2050 * 1024) return;
    int row = idx >> 10, col = idx & 1023;
    float v0 = 0.f, v1 = 0.f, v2 = 0.f, v3 = 0.f;
    if (row >= 2) {
      const float4 v = *(const float4*)(x + (size_t)(row - 2) * 1024 + col);
      v0 = v.x; v1 = v.y; v2 = v.z; v3 = v.w;
    }
    unsigned long long pk = (unsigned long long)f2bf(v0)
        | ((unsigned long long)f2bf(v1) << 16)
        | ((unsigned long long)f2bf(v2) << 32)
        | ((unsigned long long)f2bf(v3) << 48);
    *(unsigned long long*)(xb + idx) = pk;
    return;
  }
  bx -= 2050;
  if (bx < 8192) {
    int idx = bx * 256 + threadIdx.x;
    int d = idx >> 10, i = idx & 1023;
    const float* p = conv_w + (size_t)d * 3072 + (size_t)i * 3;
    unsigned short* q = cwt + (size_t)d * 3072 + i;
    q[0] = f2bf(p[0]);
    q[1024] = f2bf(p[1]);
    q[2048] = f2bf(p[2]);
    return;
  }
  bx -= 8192;
  if (bx < 128) {
    int i = bx * 256 + threadIdx.x;
    cAb[i] = log1pf(__expf(A_log[i]));  // softplus (natural log)
    return;
  }
  bx -= 128;
  const float* W;
  unsigned short* Wt;
  int src_ld, col_off, rowsI, n0, i0;
  if (bx < 2048) {
    W = in_proj_w; Wt = wzt; src_ld = 4096; col_off = 2048; rowsI = 1024;
    n0 = (bx & 63) * 32; i0 = (bx >> 6) * 32;
  } else if (bx < 2048 + 4096) {
    int b = bx - 2048;
    W = gate_w; Wt = gwt; src_ld = 2048; col_off = 0; rowsI = 2048;
    n0 = (b & 63) * 32; i0 = (b >> 6) * 32;
  } else {
    int b = bx - 2048 - 4096;
    W = o_proj_w; Wt = owt; src_ld = 1024; col_off = 0; rowsI = 2048;
    n0 = (b & 31) * 32; i0 = (b >> 5) * 32;
  }
  int tx = threadIdx.x & 31, ty = threadIdx.x >> 5;
#pragma unroll
  for (int rr = 0; rr < 32; rr += 8)
    tile[ty + rr][tx] = W[(size_t)(i0 + ty + rr) * src_ld + col_off + n0 + tx];
  __syncthreads();
#pragma unroll
  for (int rr = 0; rr < 32; rr += 8)
    Wt[(size_t)(n0 + ty + rr) * rowsI + i0 + tx] = f2bf(tile[tx][ty + rr]);
}

// ---------------- 128x128 GEMM body (2buf, 1-ahead counted vmcnt) ----------------
template <int MODE>
__device__ __forceinline__ void gemm_sq_body(
    const unsigned short* __restrict__ A, int lda,
    const unsigned short* __restrict__ Bt, int ldb, int K,
    const float* __restrict__ bias,
    float* __restrict__ outf, int ldo,
    unsigned short* __restrict__ outb,
    int bm, int bn,
    unsigned short (*As)[128 * 64], unsigned short (*Bs)[128 * 64]) {
  const int tid = threadIdx.x;
  const int lane = tid & 63;
  const int w = tid >> 6;
  const int wr = w >> 1, wc = w & 1;

  f32x4 acc[4][4];
#pragma unroll
  for (int m = 0; m < 4; ++m)
#pragma unroll
    for (int n = 0; n < 4; ++n)
#pragma unroll
      for (int j = 0; j < 4; ++j) acc[m][n][j] = 0.f;

  const int srow = lane >> 3;
  const int sslot = (lane & 7) ^ srow;
  const unsigned short* Ab = A + (size_t)(bm * 128 + srow) * lda + sslot * 8;
  const unsigned short* Bb = Bt + (size_t)(bn * 128 + srow) * ldb + sslot * 8;

  const int r = lane & 15;
  const int g = lane >> 4;
  const int nk = K >> 6;

  auto stage = [&](int buf, int k0) {
#pragma unroll
    for (int i = 0; i < 4; ++i) {
      const int cb = w * 4 + i;
      stage16(Ab + (size_t)(cb * 8) * lda + k0, &As[buf][cb * 512]);
    }
#pragma unroll
    for (int i = 0; i < 4; ++i) {
      const int cb = w * 4 + i;
      stage16(Bb + (size_t)(cb * 8) * ldb + k0, &Bs[buf][cb * 512]);
    }
  };

  auto compute = [&](int buf) {
#pragma unroll
    for (int kk = 0; kk < 64; kk += 32) {
      const int sb = (kk >> 3) + g;
      short8 af[4], bfr[4];
#pragma unroll
      for (int m = 0; m < 4; ++m) {
        const int R = wr * 64 + m * 16 + r;
        af[m] = *(const short8*)&As[buf][R * 64 + ((sb ^ (R & 7)) << 3)];
      }
#pragma unroll
      for (int n = 0; n < 4; ++n) {
        const int R = wc * 64 + n * 16 + r;
        bfr[n] = *(const short8*)&Bs[buf][R * 64 + ((sb ^ (R & 7)) << 3)];
      }
#pragma unroll
      for (int m = 0; m < 4; ++m)
#pragma unroll
        for (int n = 0; n < 4; ++n)
          acc[m][n] = __builtin_amdgcn_mfma_f32_16x16x32_bf16(af[m], bfr[n], acc[m][n], 0, 0, 0);
    }
  };

  stage(0, 0);
  int cur = 0;
  for (int kt = 0; kt < nk; ++kt) {
    if (kt + 1 < nk) {
      stage(cur ^ 1, (kt + 1) * 64);
      asm volatile("s_waitcnt vmcnt(8)" ::: "memory");
    } else {
      asm volatile("s_waitcnt vmcnt(0)" ::: "memory");
    }
    __builtin_amdgcn_s_barrier();
    __builtin_amdgcn_sched_barrier(0);
    compute(cur);
    __builtin_amdgcn_s_barrier();
    cur ^= 1;
  }

  const int cc = lane & 15;
  const int cr = g * 4;
#pragma unroll
  for (int m = 0; m < 4; ++m) {
#pragma unroll
    for (int n = 0; n < 4; ++n) {
      const int col = bn * 128 + wc * 64 + n * 16 + cc;
      const float bv = bias[col];
#pragma unroll
      for (int j = 0; j < 4; ++j) {
        const int row = bm * 128 + wr * 64 + m * 16 + cr + j;
        const size_t o = (size_t)row * ldo + col;
        float v = acc[m][n][j] + bv;
        if (MODE == 0) { outb[o] = f2bf(v); }
        else if (MODE == 1) { outf[o] = v; }
        else { outb[o] = f2bf(sigm(v)); }
      }
    }
  }
}

// conv (y<16) + z (y>=16) merged
__global__ __launch_bounds__(256, 2) void gemm_convz(
    const unsigned short* __restrict__ xb,
    const unsigned short* __restrict__ cwt,
    const unsigned short* __restrict__ wzt,
    const float* __restrict__ conv_b,
    const float* __restrict__ z_b,
    unsigned short* __restrict__ xcb,
    unsigned short* __restrict__ zpre_b) {
  __shared__ unsigned short As[2][128 * 64];
  __shared__ unsigned short Bs[2][128 * 64];
  const bool isz = blockIdx.y >= 16;
  gemm_sq_body<0>(isz ? xb + 2048 : xb, 1024,
                  isz ? wzt : cwt, isz ? 1024 : 3072, isz ? 1024 : 3072,
                  isz ? z_b : conv_b, nullptr, 2048,
                  isz ? zpre_b : xcb,
                  blockIdx.x, isz ? blockIdx.y - 16 : blockIdx.y, As, Bs);
}

// ---------------- bcdt (y<16, dispatch-first) + gate 64x64 3buf MODE3 (y in [16,48)) ----------------
#define RB 4
__global__ __launch_bounds__(256, 2) void gemm_gate64_bcdt(
    const unsigned short* __restrict__ xcb,
    const unsigned short* __restrict__ gwt,
    const float* __restrict__ gate_b,
    unsigned short* __restrict__ gpre_b,
    const float* __restrict__ xpw, const float* __restrict__ xpb,
    float* __restrict__ Bc, float* __restrict__ Cc, float* __restrict__ dt) {
  constexpr int L = 4;
  __shared__ __attribute__((aligned(16))) char smem[49152];  // 48KB
  unsigned short (*As)[4096] = (unsigned short(*)[4096])smem;
  unsigned short (*Bs)[4096] = (unsigned short(*)[4096])(smem + 24576);
  const int tid = threadIdx.x;
  const int lane = tid & 63;
  const int w = tid >> 6;

  if (blockIdx.y < 16) {
    // ---- bcdt path (512 blocks, dispatched first; LDS overlay: row 32KB + pj 4KB) ----
    float (*row)[2048] = (float(*)[2048])smem;
    float (*pj)[8][32] = (float(*)[8][32])(smem + 32768);
    const int b = blockIdx.y * 32 + blockIdx.x;  // [0,512)
    const int s0 = b * RB;
    for (int i = tid; i < RB * 256; i += 256) {
      int ri = i >> 8, c8 = i & 255;
      short8 v = *(const short8*)&xcb[(size_t)(s0 + ri) * 2048 + c8 * 8];
#pragma unroll
      for (int j = 0; j < 8; ++j) row[ri][c8 * 8 + j] = bf2f((unsigned short)v[j]);
    }
    __syncthreads();
    {
      float l = 0.f;
      for (int i = lane; i < 2048; i += 64) l += row[w][i];
#pragma unroll
      for (int off = 32; off > 0; off >>= 1) l += __shfl_down(l, off);
      if (lane == 0) dt[s0 + w] = sigm(l * (1.f / 2048.f)) + 0.001f;
    }
    const int j = tid & 31, seg = tid >> 5;
    float acc[RB] = {0.f, 0.f, 0.f, 0.f};
    const int kbase = seg * 256;
    for (int k = 0; k < 256; ++k) {
      float wv2 = xpw[(size_t)(kbase + k) * 32 + j];
#pragma unroll
      for (int ri = 0; ri < RB; ++ri) acc[ri] += row[ri][kbase + k] * wv2;
    }
#pragma unroll
    for (int ri = 0; ri < RB; ++ri) pj[ri][seg][j] = acc[ri];
    __syncthreads();
    if (tid < 32 * RB) {
      int ri = tid >> 5, jj = tid & 31;
      float v = xpb[jj];
#pragma unroll
      for (int q = 0; q < 8; ++q) v += pj[ri][q][jj];
      if (jj < 16) Bc[(size_t)(s0 + ri) * 16 + jj] = v;
      else Cc[(size_t)(s0 + ri) * 16 + jj - 16] = v;
    }
    return;
  }

  // ---- gate GEMM: 64x64, K=2048, 3-buffer 2-ahead ----
  const int wr = w >> 1, wc = w & 1;
  const int bm = blockIdx.x, bn = blockIdx.y - 16;  // bn in [0,32)

  f32x4 acc[2][2];
#pragma unroll
  for (int m = 0; m < 2; ++m)
#pragma unroll
    for (int n = 0; n < 2; ++n)
#pragma unroll
      for (int j = 0; j < 4; ++j) acc[m][n][j] = 0.f;

  const int srow = lane >> 3;
  const int sslot = (lane & 7) ^ srow;
  const unsigned short* Ab = xcb + (size_t)(bm * 64 + srow) * 2048 + sslot * 8;
  const unsigned short* Bb = gwt + (size_t)(bn * 64 + srow) * 2048 + sslot * 8;
  const int r = lane & 15;
  const int g = lane >> 4;
  const int nk = 2048 >> 6;

  auto stage = [&](int buf, int k0) {
#pragma unroll
    for (int i = 0; i < 2; ++i) {
      const int cb = w * 2 + i;
      stage16(Ab + (size_t)(cb * 8) * 2048 + k0, &As[buf][cb * 512]);
      stage16(Bb + (size_t)(cb * 8) * 2048 + k0, &Bs[buf][cb * 512]);
    }
  };
  auto compute = [&](int buf) {
#pragma unroll
    for (int kk = 0; kk < 64; kk += 32) {
      const int sb = (kk >> 3) + g;
      short8 af[2], bfr[2];
#pragma unroll
      for (int m = 0; m < 2; ++m) {
        const int R = wr * 32 + m * 16 + r;
        af[m] = *(const short8*)&As[buf][R * 64 + ((sb ^ (R & 7)) << 3)];
      }
#pragma unroll
      for (int n = 0; n < 2; ++n) {
        const int R = wc * 32 + n * 16 + r;
        bfr[n] = *(const short8*)&Bs[buf][R * 64 + ((sb ^ (R & 7)) << 3)];
      }
#pragma unroll
      for (int m = 0; m < 2; ++m)
#pragma unroll
        for (int n = 0; n < 2; ++n)
          acc[m][n] = __builtin_amdgcn_mfma_f32_16x16x32_bf16(af[m], bfr[n], acc[m][n], 0, 0, 0);
    }
  };

  stage(0, 0);
  stage(1, 64);
  int cur = 0, nxt = 2;
  for (int kt = 0; kt < nk; ++kt) {
    if (kt + 2 < nk) {
      stage(nxt, (kt + 2) * 64);
      asm volatile("s_waitcnt vmcnt(%c0)" ::"i"(2 * L) : "memory");
    } else if (kt + 1 < nk) {
      asm volatile("s_waitcnt vmcnt(%c0)" ::"i"(L) : "memory");
    } else {
      asm volatile("s_waitcnt vmcnt(0)" ::: "memory");
    }
    __builtin_amdgcn_s_barrier();
    __builtin_amdgcn_sched_barrier(0);
    compute(cur);
    __builtin_amdgcn_s_barrier();
    cur = (cur == 2) ? 0 : cur + 1;
    nxt = (nxt == 2) ? 0 : nxt + 1;
  }

  const int cc = lane & 15;
  const int cr = g * 4;
#pragma unroll
  for (int m = 0; m < 2; ++m)
#pragma unroll
    for (int n = 0; n < 2; ++n) {
      const int col = bn * 64 + wc * 32 + n * 16 + cc;
      const float bv = gate_b[col];
#pragma unroll
      for (int j = 0; j < 4; ++j) {
        const int row = bm * 64 + wr * 32 + m * 16 + cr + j;
        gpre_b[(size_t)row * 2048 + col] = f2bf(sigm(acc[m][n][j] + bv));
      }
    }
}

// ---------------- out-proj: 64x64 3-buffer counted-vmcnt ----------------
__global__ __launch_bounds__(256, 2) void gemm_out(
    const unsigned short* __restrict__ A, int lda,
    const unsigned short* __restrict__ Bt, int ldb, int K,
    const float* __restrict__ bias,
    float* __restrict__ outf, int ldo) {
  constexpr int L = 4;
  __shared__ unsigned short As[3][64 * 64];
  __shared__ unsigned short Bs[3][64 * 64];
  const int tid = threadIdx.x;
  const int lane = tid & 63;
  const int w = tid >> 6;
  const int wr = w >> 1, wc = w & 1;
  const int bm = blockIdx.x, bn = blockIdx.y;

  f32x4 acc[2][2];
#pragma unroll
  for (int m = 0; m < 2; ++m)
#pragma unroll
    for (int n = 0; n < 2; ++n)
#pragma unroll
      for (int j = 0; j < 4; ++j) acc[m][n][j] = 0.f;

  const int srow = lane >> 3;
  const int sslot = (lane & 7) ^ srow;
  const unsigned short* Ab = A + (size_t)(bm * 64 + srow) * lda + sslot * 8;
  const unsigned short* Bb = Bt + (size_t)(bn * 64 + srow) * ldb + sslot * 8;
  const int r = lane & 15;
  const int g = lane >> 4;
  const int nk = K >> 6;

  auto stage = [&](int buf, int k0) {
#pragma unroll
    for (int i = 0; i < 2; ++i) {
      const int cb = w * 2 + i;
      stage16(Ab + (size_t)(cb * 8) * lda + k0, &As[buf][cb * 512]);
      stage16(Bb + (size_t)(cb * 8) * ldb + k0, &Bs[buf][cb * 512]);
    }
  };
  auto compute = [&](int buf) {
#pragma unroll
    for (int kk = 0; kk < 64; kk += 32) {
      const int sb = (kk >> 3) + g;
      short8 af[2], bfr[2];
#pragma unroll
      for (int m = 0; m < 2; ++m) {
        const int R = wr * 32 + m * 16 + r;
        af[m] = *(const short8*)&As[buf][R * 64 + ((sb ^ (R & 7)) << 3)];
      }
#pragma unroll
      for (int n = 0; n < 2; ++n) {
        const int R = wc * 32 + n * 16 + r;
        bfr[n] = *(const short8*)&Bs[buf][R * 64 + ((sb ^ (R & 7)) << 3)];
      }
#pragma unroll
      for (int m = 0; m < 2; ++m)
#pragma unroll
        for (int n = 0; n < 2; ++n)
          acc[m][n] = __builtin_amdgcn_mfma_f32_16x16x32_bf16(af[m], bfr[n], acc[m][n], 0, 0, 0);
    }
  };

  stage(0, 0);
  stage(1, 64);
  int cur = 0, nxt = 2;
  for (int kt = 0; kt < nk; ++kt) {
    if (kt + 2 < nk) {
      stage(nxt, (kt + 2) * 64);
      asm volatile("s_waitcnt vmcnt(%c0)" ::"i"(2 * L) : "memory");
    } else if (kt + 1 < nk) {
      asm volatile("s_waitcnt vmcnt(%c0)" ::"i"(L) : "memory");
    } else {
      asm volatile("s_waitcnt vmcnt(0)" ::: "memory");
    }
    __builtin_amdgcn_s_barrier();
    __builtin_amdgcn_sched_barrier(0);
    compute(cur);
    __builtin_amdgcn_s_barrier();
    cur = (cur == 2) ? 0 : cur + 1;
    nxt = (nxt == 2) ? 0 : nxt + 1;
  }

  const int cc = lane & 15;
  const int cr = g * 4;
#pragma unroll
  for (int m = 0; m < 2; ++m)
#pragma unroll
    for (int n = 0; n < 2; ++n) {
      const int col = bn * 64 + wc * 32 + n * 16 + cc;
      const float bv = bias[col];
#pragma unroll
      for (int j = 0; j < 4; ++j) {
        const int row = bm * 64 + wr * 32 + m * 16 + cr + j;
        outf[(size_t)row * ldo + col] = acc[m][n][j] + bv;
      }
    }
}

// ---------------- scan: local pass (u = xcb * gpre; Taylor exp) ----------------
__global__ __launch_bounds__(256) void scan_local(const float* __restrict__ cAb,
                                                  const float* __restrict__ dt,
                                                  const float* __restrict__ Bc,
                                                  const float* __restrict__ Cc,
                                                  const unsigned short* __restrict__ xcb,
                                                  const unsigned short* __restrict__ gpre,
                                                  const float* __restrict__ Dp,
                                                  unsigned short* __restrict__ yloc,
                                                  unsigned short* __restrict__ Hend) {
  const int d0 = blockIdx.x * 256;
  const int d = d0 + threadIdx.x;
  const int c = blockIdx.y;
  __shared__ float sU[CT][256];
  __shared__ float sB[CT][16], sC[CT][16], sdt[CT];
  for (int i = threadIdx.x; i < CT * 32; i += 256) {
    int t = i >> 5, c8 = i & 31;
    size_t base = (size_t)(c * CT + t) * 2048 + d0 + c8 * 8;
    short8 vx = *(const short8*)&xcb[base];
    short8 vg = *(const short8*)&gpre[base];
#pragma unroll
    for (int j = 0; j < 8; ++j)
      sU[t][c8 * 8 + j] = bf2f((unsigned short)vx[j]) * bf2f((unsigned short)vg[j]);
  }
  for (int i = threadIdx.x; i < CT * 16; i += 256) {
    sB[i >> 4][i & 15] = Bc[(size_t)c * CT * 16 + i];
    sC[i >> 4][i & 15] = Cc[(size_t)c * CT * 16 + i];
  }
  if (threadIdx.x < CT) sdt[threadIdx.x] = dt[c * CT + threadIdx.x];
  __syncthreads();
  float cA[16], h[16];
#pragma unroll
  for (int n = 0; n < 16; ++n) {
    cA[n] = cAb[(size_t)d * 16 + n];
    h[n] = 0.f;
  }
  const float Dv = Dp[d];
  for (int t = 0; t < CT; ++t) {
    const float dtv = sdt[t];
    const float uv = sU[t][threadIdx.x];
    const float du = dtv * uv;
    float y = Dv * uv;
#pragma unroll
    for (int n = 0; n < 16; ++n) {
      float ab = exps(cA[n] * dtv);
      h[n] = ab * (h[n] + sB[t][n] * du);
      y += h[n] * sC[t][n];
    }
    yloc[(size_t)(c * CT + t) * 2048 + d] = f2bf(y);
  }
#pragma unroll
  for (int n = 0; n < 16; ++n) Hend[(size_t)c * 32768 + (size_t)d * 16 + n] = f2bf(h[n]);
}

// ---------------- scan: carry (in-place, bf16 H, Taylor exp) ----------------
__global__ __launch_bounds__(256) void scan_carry(const float* __restrict__ cAb,
                                                  const float* __restrict__ dt,
                                                  unsigned short* H) {
  const int g = blockIdx.x * 256 + threadIdx.x;
  __shared__ float sdt[2048];
  __shared__ float sS[NCH];
  for (int i = threadIdx.x; i < 2048; i += 256) sdt[i] = dt[i];
  __syncthreads();
  if (threadIdx.x < NCH) {
    float s = 0.f;
#pragma unroll
    for (int t = 0; t < CT; ++t) s += sdt[threadIdx.x * CT + t];
    sS[threadIdx.x] = s;
  }
  __syncthreads();
  const float cA = cAb[g];
  float h = 0.f;
  for (int cb = 0; cb < NCH; cb += 16) {
    float hl[16];
#pragma unroll
    for (int i = 0; i < 16; ++i) hl[i] = bf2f(H[(size_t)(cb + i) * 32768 + g]);
#pragma unroll
    for (int i = 0; i < 16; ++i) {
      H[(size_t)(cb + i) * 32768 + g] = f2bf(h);
      h = exps(cA * sS[cb + i]) * h + hl[i];
    }
  }
}

// ---------------- scan: final (parallel correction + gate, Taylor exp) ----------------
__global__ __launch_bounds__(256) void scan_final(const float* __restrict__ cAb,
                                                  const float* __restrict__ dt,
                                                  const float* __restrict__ Cc,
                                                  const unsigned short* __restrict__ yloc,
                                                  const unsigned short* __restrict__ zpre,
                                                  const unsigned short* __restrict__ H,
                                                  unsigned short* __restrict__ ob) {
  const int d = blockIdx.x * 256 + threadIdx.x;
  const int c = blockIdx.y;
  __shared__ float sC[CT][16], sT[CT], sdt[CT];
  for (int i = threadIdx.x; i < CT * 16; i += 256) sC[i >> 4][i & 15] = Cc[(size_t)c * CT * 16 + i];
  if (threadIdx.x < CT) sdt[threadIdx.x] = dt[c * CT + threadIdx.x];
  __syncthreads();
  if (threadIdx.x < CT) {
    float a = 0.f;
    for (int t = 0; t <= threadIdx.x; ++t) a += sdt[t];
    sT[threadIdx.x] = a;
  }
  __syncthreads();
  float cA[16], h0[16];
#pragma unroll
  for (int n = 0; n < 16; ++n) {
    cA[n] = cAb[(size_t)d * 16 + n];
    h0[n] = bf2f(H[(size_t)c * 32768 + (size_t)d * 16 + n]);
  }
  for (int t = 0; t < CT; ++t) {
    const size_t idx = (size_t)(c * CT + t) * 2048 + d;
    const float Tt = sT[t];
    float y = bf2f(yloc[idx]);
#pragma unroll
    for (int n = 0; n < 16; ++n) y += sC[t][n] * exps(cA[n] * Tt) * h0[n];
    ob[idx] = f2bf(y * sigm(bf2f(zpre[idx])));
  }
}

// ---------------- launch ----------------
extern "C" void kernel_launch(void* const* d_in, const int* in_sizes, int n_in,
                              void* d_out, int out_size, void* d_ws, size_t ws_size,
                              hipStream_t stream) {
  (void)in_sizes; (void)n_in; (void)out_size; (void)ws_size;
  const float* x = (const float*)d_in[0];
  const float* in_proj_w = (const float*)d_in[1];
  const float* in_proj_b = (const float*)d_in[2];
  const float* conv_w = (const float*)d_in[3];
  const float* conv_b = (const float*)d_in[4];
  const float* A_log = (const float*)d_in[5];
  const float* Dp = (const float*)d_in[6];
  const float* x_proj_w = (const float*)d_in[7];
  const float* x_proj_b = (const float*)d_in[8];
  const float* gate_w = (const float*)d_in[9];
  const float* gate_b = (const float*)d_in[10];
  const float* o_proj_w = (const float*)d_in[11];
  const float* o_proj_b = (const float*)d_in[12];

  char* ws = (char*)d_ws;
  size_t off = 0;
  unsigned short* xb = (unsigned short*)(ws + off); off += (size_t)2050 * 1024 * 2;
  off = (off + 255) & ~(size_t)255;
  unsigned short* cwt = (unsigned short*)(ws + off); off += (size_t)2048 * 3072 * 2;
  unsigned short* wzt = (unsigned short*)(ws + off); off += (size_t)2048 * 1024 * 2;
  unsigned short* gwt = (unsigned short*)(ws + off); off += (size_t)2048 * 2048 * 2;
  unsigned short* owt = (unsigned short*)(ws + off); off += (size_t)1024 * 2048 * 2;
  unsigned short* xcb = (unsigned short*)(ws + off); off += (size_t)2048 * 2048 * 2;
  unsigned short* zpre_b = (unsigned short*)(ws + off); off += (size_t)2048 * 2048 * 2;
  unsigned short* gpre_b = (unsigned short*)(ws + off); off += (size_t)2048 * 2048 * 2;
  unsigned short* yloc = (unsigned short*)(ws + off); off += (size_t)2048 * 2048 * 2;
  float* dtv = (float*)(ws + off); off += (size_t)2048 * 4;
  float* Bc = (float*)(ws + off); off += (size_t)2048 * 16 * 4;
  float* Cc = (float*)(ws + off); off += (size_t)2048 * 16 * 4;
  float* cAb = (float*)(ws + off); off += (size_t)32768 * 4;
  unsigned short* H = (unsigned short*)(ws + off); off += (size_t)NCH * 32768 * 2;
  unsigned short* ob = yloc;  // alias: scan_final reads yloc[idx] before writing ob[idx]

  prep_uber<<<18562, 256, 0, stream>>>(x, conv_w, A_log, in_proj_w, gate_w, o_proj_w,
                                       xb, cwt, cAb, wzt, gwt, owt);

  // conv [K=3072] + z [K=1024] merged: 1024 blocks, 2/CU (best-known config)
  gemm_convz<<<dim3(16, 32), 256, 0, stream>>>(xb, cwt, wzt, conv_b, in_proj_b + 2048, xcb, zpre_b);

  // bcdt (y<16, dispatch-first) + gate 64x64 (y in [16,48))
  gemm_gate64_bcdt<<<dim3(32, 48), 256, 0, stream>>>(xcb, gwt, gate_b, gpre_b,
                                                     x_proj_w, x_proj_b, Bc, Cc, dtv);

  scan_local<<<dim3(8, NCH), 256, 0, stream>>>(cAb, dtv, Bc, Cc, xcb, gpre_b, Dp, yloc, H);
  scan_carry<<<128, 256, 0, stream>>>(cAb, dtv, H);
  scan_final<<<dim3(8, NCH), 256, 0, stream>>>(cAb, dtv, Cc, yloc, zpre_b, H, ob);

  // output projection [2048x1024, K=2048]
  gemm_out<<<dim3(32, 16), 256, 0, stream>>>(ob, 2048, owt, 2048, 2048, o_proj_b, (float*)d_out, 1024);
}